// Round 6
// baseline (55983.685 us; speedup 1.0000x reference)
//
#include <hip/hip_runtime.h>
#include <math.h>

#define TT 2048
#define DIN 64
#define HH 256

typedef __attribute__((ext_vector_type(8))) short bf16x8;
typedef __attribute__((ext_vector_type(4))) float f32x4;
typedef unsigned u32t;
typedef unsigned short u16;

#define MFMA16(a,b,c_) __builtin_amdgcn_mfma_f32_16x16x32_bf16(a,b,c_,0,0,0)

__device__ __forceinline__ u16 f2bf(float f){
    u32t u = __builtin_bit_cast(u32t, f);
    u += 0x7fffu + ((u >> 16) & 1u);   // RNE
    return (u16)(u >> 16);
}
__device__ __forceinline__ float bf2f(u16 h){
    u32t u = ((u32t)h) << 16;
    return __builtin_bit_cast(float, u);
}
__device__ __forceinline__ float sigf(float v){ return 1.0f/(1.0f+__expf(-v)); }
__device__ __forceinline__ float tanhfast(float v){
    float x = fminf(fmaxf(v, -15.f), 15.f);
    float t = __expf(2.f*x);
    return (t - 1.f) / (t + 1.f);
}
__device__ __forceinline__ void split8(float4 a, float4 b, bf16x8& hi, bf16x8& lo){
    float v[8] = {a.x,a.y,a.z,a.w,b.x,b.y,b.z,b.w};
    #pragma unroll
    for (int j=0;j<8;++j){
        u16 h = f2bf(v[j]);
        hi[j] = (short)h;
        lo[j] = (short)f2bf(v[j] - bf2f(h));
    }
}
// 8 packed u32 (bf16hi<<16 | bf16lo) -> two bf16x8 fragments
__device__ __forceinline__ void unpack8(uint4 a, uint4 b, bf16x8& hi, bf16x8& lo){
    uint4 h, l;
    h.x = __builtin_amdgcn_perm(a.y, a.x, 0x07060302u);
    h.y = __builtin_amdgcn_perm(a.w, a.z, 0x07060302u);
    h.z = __builtin_amdgcn_perm(b.y, b.x, 0x07060302u);
    h.w = __builtin_amdgcn_perm(b.w, b.z, 0x07060302u);
    l.x = __builtin_amdgcn_perm(a.y, a.x, 0x05040100u);
    l.y = __builtin_amdgcn_perm(a.w, a.z, 0x05040100u);
    l.z = __builtin_amdgcn_perm(b.y, b.x, 0x05040100u);
    l.w = __builtin_amdgcn_perm(b.w, b.z, 0x05040100u);
    hi = __builtin_bit_cast(bf16x8, h);
    lo = __builtin_bit_cast(bf16x8, l);
}

__device__ __forceinline__ void group_barrier(u32t* flg, int ug, unsigned epoch){
    __syncthreads();                      // drains all waves' vm/lgkm before flag
    if (threadIdx.x == 0)
        __hip_atomic_store(flg + ug, epoch, __ATOMIC_RELEASE, __HIP_MEMORY_SCOPE_AGENT);
    if (threadIdx.x < 64) {
        while (__hip_atomic_load(flg + threadIdx.x, __ATOMIC_ACQUIRE, __HIP_MEMORY_SCOPE_AGENT) < epoch)
            __builtin_amdgcn_s_sleep(2);
    }
    __syncthreads();
}

template<int N>
__device__ __forceinline__ void mm_h(const u32t* hp, int ub0, const short* wlo,
                                     const bf16x8* wh, f32x4* ac){
    #pragma unroll
    for (int i=0;i<N;++i){
        const u32t* p = hp + ub0 + i*32;
        uint4 pa = *(const uint4*)p;
        uint4 pb = *(const uint4*)(p+4);
        bf16x8 ah, al; unpack8(pa, pb, ah, al);
        bf16x8 wl = *(const bf16x8*)(wlo + i*512);
        f32x4 t = ac[i&3];
        t = MFMA16(ah, wh[i], t);
        t = MFMA16(al, wh[i], t);
        t = MFMA16(ah, wl,    t);
        ac[i&3] = t;
    }
}

__global__ __launch_bounds__(256, 2)
void lstm_v6(const float* __restrict__ x,
             const float* __restrict__ Wih0, const float* __restrict__ Whh0,
             const float* __restrict__ bih0, const float* __restrict__ bhh0,
             const float* __restrict__ Wih1, const float* __restrict__ Whh1,
             const float* __restrict__ bih1, const float* __restrict__ bhh1,
             const float* __restrict__ Wd,   const float* __restrict__ bd,
             float* __restrict__ out, u32t* __restrict__ hb,
             u32t* __restrict__ flags)
{
    __shared__ short swlo[13312];   // W0lo: 640 frags, W1lo: 1024 frags, 16B each

    const int tid = threadIdx.x;
    const int w   = blockIdx.x;
    const int rb  = w & 7;          // row-group (XCD-affine under round-robin)
    const int ug  = w >> 3;         // 0..63 -> 4 hidden units each
    const int rbase = rb * 32;
    const int u0  = ug * 4;

    u32t* flg = flags + rb * 1024;  // 4KB-spaced per-group flag arrays
    u32t* h0p = hb;                 // [2 parity][65536] packed u32
    u32t* h1p = hb + 131072;

    const int l   = tid & 63;
    const int wid = tid >> 6;
    const int lay = wid >> 1;       // 0: layer0, 1: layer1
    const int mt  = wid & 1;        // 16-row half
    const int c   = l & 15;         // col in tile
    const int kg  = l >> 4;         // k-group 0..3
    const int hk8 = kg * 8;
    const int b   = c >> 2;         // own gate (0=i,1=f,2=g,3=o)
    const int G   = b*HH + u0 + (c&3);   // gate-row in weight matrices

    // ---- stationary HI weight fragments in registers ----
    bf16x8 wh[16];
    if (lay == 0){
        #pragma unroll
        for (int kt=0; kt<10; ++kt){
            int k = kt*32 + hk8;
            const float* p = (k < 64) ? (Wih0 + (size_t)G*DIN + k)
                                      : (Whh0 + (size_t)G*HH + (k-64));
            bf16x8 hi_, lo_; split8(*(const float4*)p, *(const float4*)(p+4), hi_, lo_);
            wh[kt] = hi_;
        }
    } else {
        #pragma unroll
        for (int kt=0; kt<16; ++kt){
            int k = kt*32 + hk8;
            const float* p = (k < 256) ? (Wih1 + (size_t)G*HH + k)
                                       : (Whh1 + (size_t)G*HH + (k-256));
            bf16x8 hi_, lo_; split8(*(const float4*)p, *(const float4*)(p+4), hi_, lo_);
            wh[kt] = hi_;
        }
    }
    const float bs = (lay==0) ? (bih0[G] + bhh0[G]) : (bih1[G] + bhh1[G]);

    // ---- LO weight fragments -> LDS [kt][lane][8] ----
    for (int f = tid; f < 640; f += 256){
        int kt = f >> 6, ll = f & 63;
        int c2 = ll & 15;
        int G2 = (c2>>2)*HH + u0 + (c2&3);
        int k  = kt*32 + (ll>>4)*8;
        const float* p = (k < 64) ? (Wih0 + (size_t)G2*DIN + k)
                                  : (Whh0 + (size_t)G2*HH + (k-64));
        bf16x8 hi_, lo_; split8(*(const float4*)p, *(const float4*)(p+4), hi_, lo_);
        *(bf16x8*)(swlo + f*8) = lo_;
    }
    for (int f = tid; f < 1024; f += 256){
        int kt = f >> 6, ll = f & 63;
        int c2 = ll & 15;
        int G2 = (c2>>2)*HH + u0 + (c2&3);
        int k  = kt*32 + (ll>>4)*8;
        const float* p = (k < 256) ? (Wih1 + (size_t)G2*HH + k)
                                   : (Whh1 + (size_t)G2*HH + (k-256));
        bf16x8 hi_, lo_; split8(*(const float4*)p, *(const float4*)(p+4), hi_, lo_);
        *(bf16x8*)(swlo + 5120 + f*8) = lo_;
    }

    // ---- zero OWN group's h slices (ws poisoned); 512 u32 per WG ----
    {
        int t = tid;
        #pragma unroll
        for (int jj=0; jj<2; ++jj, t += 256){
            int q   = ug*512 + t;            // 0..32767 within group
            int s   = q >> 13;               // slice: layer=s>>1, parity=s&1
            int idx = q & 8191;
            int row = idx >> 8, uq = idx & 255;
            hb[(size_t)(s>>1)*131072 + (s&1)*65536 + (size_t)(rbase+row)*HH + uq] = 0u;
        }
    }

    // ---- x(0) prefetch into registers (layer-0 waves) ----
    const float* xbase = x + (size_t)(rbase + mt*16 + c)*(TT*DIN) + hk8;
    bf16x8 x0h, x0l, x1h, x1l;
    if (lay == 0){
        split8(*(const float4*)(xbase),    *(const float4*)(xbase+4),  x0h, x0l);
        split8(*(const float4*)(xbase+32), *(const float4*)(xbase+36), x1h, x1l);
    }

    group_barrier(flg, ug, 1u);

    const size_t rowA = (size_t)(rbase + mt*16 + c) * HH;  // A-frag row offset
    const int prow = rbase + mt*16 + kg*4;                 // publish rows base
    float cs[4] = {0.f, 0.f, 0.f, 0.f};

    for (int k = 0; k <= TT; ++k){
        const int act = (lay==0) ? (k < TT) : (k >= 1);
        if (act){
            f32x4 ac[4] = {};
            float4 na, nb, nc_, nd;
            const bool pf = (lay==0) && (k+1 < TT);
            if (lay == 0){
                // x tiles kt0,kt1 (registers)
                bf16x8 wl0 = *(const bf16x8*)(swlo + 0*512 + l*8);
                bf16x8 wl1 = *(const bf16x8*)(swlo + 1*512 + l*8);
                f32x4 t0 = ac[0];
                t0 = MFMA16(x0h, wh[0], t0); t0 = MFMA16(x0l, wh[0], t0); t0 = MFMA16(x0h, wl0, t0);
                ac[0] = t0;
                f32x4 t1 = ac[1];
                t1 = MFMA16(x1h, wh[1], t1); t1 = MFMA16(x1l, wh[1], t1); t1 = MFMA16(x1h, wl1, t1);
                ac[1] = t1;
                // issue next-step x loads (latency hides under h-part MFMA)
                if (pf){
                    const float* xp = xbase + (size_t)(k+1)*DIN;
                    na  = *(const float4*)(xp);
                    nb  = *(const float4*)(xp+4);
                    nc_ = *(const float4*)(xp+32);
                    nd  = *(const float4*)(xp+36);
                }
                // h0(k-1) recurrent part, kt2..9
                const u32t* hp0 = h0p + ((k+1)&1)*65536 + rowA;
                mm_h<8>(hp0, hk8, swlo + 2*512 + l*8, wh+2, ac);
            } else {
                // layer1 step t=k-1: inputs h0(k-1), h1(k-2)
                const u32t* hp0 = h0p + ((k+1)&1)*65536 + rowA;
                const u32t* hp1 = h1p + (k&1)*65536 + rowA;
                mm_h<8>(hp0, hk8, swlo + 5120 + l*8,          wh,   ac);
                mm_h<8>(hp1, hk8, swlo + 5120 + 8*512 + l*8,  wh+8, ac);
            }
            f32x4 aa = (ac[0]+ac[1]) + (ac[2]+ac[3]);
            // in-register gate recombine + cell update + packed publish
            u32t* wp = (lay==0) ? (h0p + (k&1)*65536) : (h1p + ((k+1)&1)*65536);
            #pragma unroll
            for (int r=0; r<4; ++r){
                float v = aa[r] + bs;
                int vi = __builtin_bit_cast(int, v);
                float f4  = __builtin_bit_cast(float, __builtin_amdgcn_ds_swizzle(vi, 0x101F));
                float f8  = __builtin_bit_cast(float, __builtin_amdgcn_ds_swizzle(vi, 0x201F));
                float f12 = __builtin_bit_cast(float, __builtin_amdgcn_ds_swizzle(vi, 0x301F));
                float gi = (b==0) ? v   : (b==1) ? f4  : (b==2) ? f8  : f12;
                float gf = (b==0) ? f4  : (b==1) ? v   : (b==2) ? f12 : f8;
                float gg = (b==0) ? f8  : (b==1) ? f12 : (b==2) ? v   : f4;
                float go = (b==0) ? f12 : (b==1) ? f8  : (b==2) ? f4  : v;
                cs[r] = sigf(gf)*cs[r] + sigf(gi)*tanhfast(gg);
                float hn = sigf(go)*tanhfast(cs[r]);
                if (b == 0){
                    u16 hh_ = f2bf(hn);
                    u16 hl_ = f2bf(hn - bf2f(hh_));
                    wp[(size_t)(prow + r)*HH + u0 + c] = ((u32t)hh_ << 16) | (u32t)hl_;
                }
            }
            if (pf){
                split8(na, nb, x0h, x0l);
                split8(nc_, nd, x1h, x1l);
            }
        }
        group_barrier(flg, ug, (unsigned)(k+2));
    }

    // ---- dense head: out = h1(TT-1) @ Wd^T + bd ; parity (TT-1)&1 = 1 ----
    if (w < 8 && tid < 64){
        int r = tid >> 1, j = tid & 1;
        const u32t* hp = h1p + 65536 + (size_t)(rbase + r)*HH;
        const float* wdp = Wd + j*HH;
        float a = bd[j];
        #pragma unroll 4
        for (int q = 0; q < HH; ++q){
            u32t pv = hp[q];
            a += (bf2f((u16)(pv >> 16)) + bf2f((u16)(pv & 0xffff))) * wdp[q];
        }
        out[(rbase + r)*2 + j] = a;
    }
}

extern "C" void kernel_launch(void* const* d_in, const int* in_sizes, int n_in,
                              void* d_out, int out_size, void* d_ws, size_t ws_size,
                              hipStream_t stream) {
    const float* x    = (const float*)d_in[0];
    const float* Wih0 = (const float*)d_in[1];
    const float* Whh0 = (const float*)d_in[2];
    const float* bih0 = (const float*)d_in[3];
    const float* bhh0 = (const float*)d_in[4];
    const float* Wih1 = (const float*)d_in[5];
    const float* Whh1 = (const float*)d_in[6];
    const float* bih1 = (const float*)d_in[7];
    const float* bhh1 = (const float*)d_in[8];
    const float* Wd   = (const float*)d_in[9];
    const float* bd   = (const float*)d_in[10];
    float* out = (float*)d_out;

    u32t* flags = (u32t*)d_ws;                     // 8 groups x 64 slots, 4KB spacing
    u32t* hb    = (u32t*)((char*)d_ws + 32768);    // 1MB packed h planes

    hipMemsetAsync(d_ws, 0, 32768, stream);

    lstm_v6<<<dim3(512), dim3(256), 0, stream>>>(
        x, Wih0, Whh0, bih0, bhh0, Wih1, Whh1, bih1, bhh1,
        Wd, bd, out, hb, flags);
}

// Round 7
// 23069.864 us; speedup vs baseline: 2.4267x; 2.4267x over previous
//
#include <hip/hip_runtime.h>
#include <math.h>

#define TT 2048
#define DIN 64
#define HH 256

typedef __attribute__((ext_vector_type(8))) short bf16x8;
typedef __attribute__((ext_vector_type(4))) float f32x4;
typedef unsigned u32t;
typedef unsigned short u16;

// ---- LDS layout (shorts region, then floats region) ----
// Fragment-order staging: [plane][kt][mt][lane(ks*16+c)][8 shorts]
// -> every A-fragment read is one contiguous 1KB wave-linear ds_read_b128 (0 conflicts)
#define OFF_XS    0        // [parity2][plane2][kt2][mt2][64][8] : 8192 shorts
#define OFF_H0    8192     // [plane2][kt8][mt2][64][8]          : 16384
#define OFF_H1    24576    // [plane2][kt8][mt2][64][8]          : 16384
#define OFF_W0LO  40960    // 10 kt * 128 slots * 8              : 10240
#define OFF_W1LO  51200    // 16 kt * 128 slots * 8              : 16384
#define SH_SHORTS 67584
#define SH_BYTES  (SH_SHORTS*2)         // 135168 B
#define GB_STR 36                        // gate buffer row stride (32+4)
#define LDS_BYTES (SH_BYTES + 2368*4)   // + gb0,gb1,biases = 144640 B

__device__ __forceinline__ u16 f2bf(float f){
    u32t u = __builtin_bit_cast(u32t, f);
    u += 0x7fffu + ((u >> 16) & 1u);   // RNE
    return (u16)(u >> 16);
}
__device__ __forceinline__ float bf2f(u16 h){
    u32t u = ((u32t)h) << 16;
    return __builtin_bit_cast(float, u);
}
__device__ __forceinline__ float sigf(float v){ return 1.0f/(1.0f+__expf(-v)); }

__device__ __forceinline__ void split8(float4 a, float4 b, bf16x8& hi, bf16x8& lo){
    float v[8] = {a.x,a.y,a.z,a.w,b.x,b.y,b.z,b.w};
    #pragma unroll
    for (int j=0;j<8;++j){
        u16 h = f2bf(v[j]);
        hi[j] = (short)h;
        lo[j] = (short)f2bf(v[j] - bf2f(h));
    }
}

// flag-array group barrier: one release store per WG (64B-spaced slot),
// 32-lane parallel acquire poll. No serialized atomic RMW chain.
__device__ __forceinline__ void group_barrier(u32t* flg, int ug, unsigned epoch){
    __syncthreads();   // drains vmcnt for all waves -> publishes visible at L2
    if (threadIdx.x == 0)
        __hip_atomic_store(flg + ug*16, epoch, __ATOMIC_RELEASE, __HIP_MEMORY_SCOPE_AGENT);
    if (threadIdx.x < 32) {
        while (__hip_atomic_load(flg + threadIdx.x*16, __ATOMIC_ACQUIRE, __HIP_MEMORY_SCOPE_AGENT) < epoch)
            __builtin_amdgcn_s_sleep(1);
    }
    __syncthreads();
}

#define MFMA16(a,b,c_) __builtin_amdgcn_mfma_f32_16x16x32_bf16(a,b,c_,0,0,0)

__global__ __launch_bounds__(256, 1)
void lstm_v7(const float* __restrict__ x,
             const float* __restrict__ Wih0, const float* __restrict__ Whh0,
             const float* __restrict__ bih0, const float* __restrict__ bhh0,
             const float* __restrict__ Wih1, const float* __restrict__ Whh1,
             const float* __restrict__ bih1, const float* __restrict__ bhh1,
             const float* __restrict__ Wd,   const float* __restrict__ bd,
             float* __restrict__ out, u16* __restrict__ hb,
             u32t* __restrict__ flags)
{
    extern __shared__ char smem[];
    short* sh  = (short*)smem;
    float* sf  = (float*)(smem + SH_BYTES);
    float* gb0 = sf;             // [32][36]
    float* gb1 = sf + 1152;      // [32][36]
    float* b0s = sf + 2304;      // [32]
    float* b1s = sf + 2336;      // [32]

    const int tid = threadIdx.x;
    const int w   = blockIdx.x;
    const int rb  = w & 7;      // row-group (all 32 WGs of a group land on one XCD)
    const int ug  = w >> 3;     // unit-group 0..31
    const int rbase = rb * 32;
    const int u0  = ug * 8;

    u32t* flg = flags + rb * 512;

    // h planes in ws (u16): h0hi,h0lo,h1hi,h1lo at p*131072, + parity*65536

    // ---- per-lane MFMA ids (identical to r4-verified mapping) ----
    const int l  = tid & 63;
    const int wv = tid >> 6;          // wave 0..3
    const int mt = wv >> 1, nt = wv & 1;
    const int c  = l & 15, ks = l >> 4;
    const int gbx = nt*2 + (c >> 3);  // gate block
    const int g   = gbx*HH + u0 + (c & 7);

    // ---- stationary HI weight fragments in registers ----
    bf16x8 w0h[10];
    #pragma unroll
    for (int kt = 0; kt < 10; ++kt) {
        int k = kt*32 + ks*8;
        const float* p = (k < 64) ? (Wih0 + (size_t)g*64 + k)
                                  : (Whh0 + (size_t)g*HH + (k - 64));
        bf16x8 hi_, lo_;
        split8(*(const float4*)p, *(const float4*)(p+4), hi_, lo_);
        w0h[kt] = hi_;
    }
    bf16x8 w1h[16];
    #pragma unroll
    for (int kt = 0; kt < 16; ++kt) {
        int k = kt*32 + ks*8;
        const float* p = (k < 256) ? (Wih1 + (size_t)g*HH + k)
                                   : (Whh1 + (size_t)g*HH + (k - 256));
        bf16x8 hi_, lo_;
        split8(*(const float4*)p, *(const float4*)(p+4), hi_, lo_);
        w1h[kt] = hi_;
    }
    // ---- LO weight fragments into LDS, slot = kt*128 + nt*64 + ks*16 + c ----
    for (int f = tid; f < 1280; f += 256) {
        int c_ = f & 15, ks_ = (f>>4)&3, nt_ = (f>>6)&1, kt_ = f>>7;
        int g_ = (nt_*2 + (c_>>3))*HH + u0 + (c_&7);
        int k_ = kt_*32 + ks_*8;
        const float* p = (k_ < 64) ? (Wih0 + (size_t)g_*64 + k_)
                                   : (Whh0 + (size_t)g_*HH + (k_ - 64));
        bf16x8 hi_, lo_;
        split8(*(const float4*)p, *(const float4*)(p+4), hi_, lo_);
        *(bf16x8*)(sh + OFF_W0LO + f*8) = lo_;
    }
    for (int f = tid; f < 2048; f += 256) {
        int c_ = f & 15, ks_ = (f>>4)&3, nt_ = (f>>6)&1, kt_ = f>>7;
        int g_ = (nt_*2 + (c_>>3))*HH + u0 + (c_&7);
        int k_ = kt_*32 + ks_*8;
        const float* p = (k_ < 256) ? (Wih1 + (size_t)g_*HH + k_)
                                    : (Whh1 + (size_t)g_*HH + (k_ - 256));
        bf16x8 hi_, lo_;
        split8(*(const float4*)p, *(const float4*)(p+4), hi_, lo_);
        *(bf16x8*)(sh + OFF_W1LO + f*8) = lo_;
    }

    if (tid < 32) {
        int gg_ = (tid >> 3)*HH + u0 + (tid & 7);
        b0s[tid] = bih0[gg_] + bhh0[gg_];
        b1s[tid] = bih1[gg_] + bhh1[gg_];
    }
    // ---- zero my h slots in all planes/parities (ws poisoned) ----
    {
        int zr = tid >> 3, zu = tid & 7;
        size_t off = (size_t)(rbase + zr)*HH + u0 + zu;
        hb[off] = 0; hb[65536 + off] = 0;
        hb[131072 + off] = 0; hb[196608 + off] = 0;
        hb[262144 + off] = 0; hb[327680 + off] = 0;
        hb[393216 + off] = 0; hb[458752 + off] = 0;
    }
    // ---- stage x(0) into parity 0, fragment order ----
    {
        int r = tid & 31, c8 = tid >> 5;            // c8 0..7
        const float* xp = x + (size_t)(rbase + r)*(TT*DIN) + c8*8;
        bf16x8 xh, xl;
        split8(*(const float4*)xp, *(const float4*)(xp+4), xh, xl);
        int fo = ((c8>>2)*2 + (r>>4))*512 + ((c8&3)*16 + (r&15))*8;
        *(bf16x8*)(sh + OFF_XS + fo)        = xh;
        *(bf16x8*)(sh + OFF_XS + 2048 + fo) = xl;
    }
    group_barrier(flg, ug, 1u);

    // A-frag wave base pointers (lane-linear; kt stride = 1024 shorts)
    const short* h0A = sh + OFF_H0 + mt*512 + l*8;   // hi plane; lo = +8192
    const short* h1A = sh + OFF_H1 + mt*512 + l*8;
    const short* b0lo = sh + OFF_W0LO + (nt*64 + ks*16 + c)*8;  // kt stride 1024
    const short* b1lo = sh + OFF_W1LO + (nt*64 + ks*16 + c)*8;
    // D-tile -> gate buffer write pointers (r4-verified mapping)
    float* gw0 = gb0 + (mt*16 + ks*4)*GB_STR + nt*16 + c;
    float* gw1 = gb1 + (mt*16 + ks*4)*GB_STR + nt*16 + c;
    // cell-update mapping
    const int ur = tid >> 3, uu = tid & 7;
    const size_t poff = (size_t)(rbase + ur)*HH + u0 + uu;

    float c0s = 0.f, c1s = 0.f;

    for (int k = 0; k <= TT; ++k) {
        // ---- stage h0(k-1), h1(k-2) into fragment layout (parity rd) ----
        {
            const unsigned rdo = ((k + 1) & 1) * 65536u;
            #pragma unroll
            for (int j = 0; j < 4; ++j) {
                int idx = tid + j*256;          // 0..1023
                int r = idx & 31, c8 = idx >> 5;   // c8 0..31
                size_t goff = (size_t)(rbase + r)*HH + c8*8;
                int fo = ((c8>>2)*2 + (r>>4))*512 + ((c8&3)*16 + (r&15))*8;
                *(uint4*)(sh + OFF_H0 + fo)         = *(const uint4*)(hb + rdo + goff);
                *(uint4*)(sh + OFF_H0 + 8192 + fo)  = *(const uint4*)(hb + 131072 + rdo + goff);
                *(uint4*)(sh + OFF_H1 + fo)         = *(const uint4*)(hb + 262144 + rdo + goff);
                *(uint4*)(sh + OFF_H1 + 8192 + fo)  = *(const uint4*)(hb + 393216 + rdo + goff);
            }
        }
        __syncthreads();

        // ---- phase A: layer0 step t=k ----
        if (k < TT) {
            const short* xA = sh + OFF_XS + (k&1)*4096 + mt*512 + l*8;
            f32x4 ac[4] = {};
            #pragma unroll
            for (int kt = 0; kt < 10; ++kt) {
                const short* ph = (kt < 2) ? (xA + kt*1024) : (h0A + (kt-2)*1024);
                const short* pl = ph + ((kt < 2) ? 2048 : 8192);
                bf16x8 ah = *(const bf16x8*)ph;
                bf16x8 al = *(const bf16x8*)pl;
                bf16x8 wl = *(const bf16x8*)(b0lo + kt*1024);
                const int q = kt & 3;
                ac[q] = MFMA16(ah, w0h[kt], ac[q]);
                ac[q] = MFMA16(al, w0h[kt], ac[q]);
                ac[q] = MFMA16(ah, wl,      ac[q]);
            }
            f32x4 aa = (ac[0] + ac[1]) + (ac[2] + ac[3]);
            gw0[0]        = aa[0];
            gw0[GB_STR]   = aa[1];
            gw0[2*GB_STR] = aa[2];
            gw0[3*GB_STR] = aa[3];
        }
        // ---- phase B: layer1 step t=k-1 ----
        if (k >= 1) {
            f32x4 ac[4] = {};
            #pragma unroll
            for (int kt = 0; kt < 16; ++kt) {
                const short* ph = (kt < 8) ? (h0A + kt*1024) : (h1A + (kt-8)*1024);
                const short* pl = ph + 8192;
                bf16x8 ah = *(const bf16x8*)ph;
                bf16x8 al = *(const bf16x8*)pl;
                bf16x8 wl = *(const bf16x8*)(b1lo + kt*1024);
                const int q = kt & 3;
                ac[q] = MFMA16(ah, w1h[kt], ac[q]);
                ac[q] = MFMA16(al, w1h[kt], ac[q]);
                ac[q] = MFMA16(ah, wl,      ac[q]);
            }
            f32x4 aa = (ac[0] + ac[1]) + (ac[2] + ac[3]);
            gw1[0]        = aa[0];
            gw1[GB_STR]   = aa[1];
            gw1[2*GB_STR] = aa[2];
            gw1[3*GB_STR] = aa[3];
        }
        __syncthreads();

        // ---- cell updates + publish (hi/lo bf16 planes, parity wr) ----
        const unsigned wro = (k & 1) * 65536u;
        if (k < TT) {
            float gi = gb0[ur*GB_STR + uu]      + b0s[uu];
            float gf = gb0[ur*GB_STR + 8 + uu]  + b0s[8+uu];
            float gg = gb0[ur*GB_STR + 16 + uu] + b0s[16+uu];
            float go = gb0[ur*GB_STR + 24 + uu] + b0s[24+uu];
            c0s = sigf(gf)*c0s + sigf(gi)*tanhf(gg);
            float hn = sigf(go)*tanhf(c0s);
            u16 hh_ = f2bf(hn);
            u16 hl_ = f2bf(hn - bf2f(hh_));
            (hb + wro)[poff]          = hh_;
            (hb + 131072 + wro)[poff] = hl_;
        }
        if (k >= 1) {
            float gi = gb1[ur*GB_STR + uu]      + b1s[uu];
            float gf = gb1[ur*GB_STR + 8 + uu]  + b1s[8+uu];
            float gg = gb1[ur*GB_STR + 16 + uu] + b1s[16+uu];
            float go = gb1[ur*GB_STR + 24 + uu] + b1s[24+uu];
            c1s = sigf(gf)*c1s + sigf(gi)*tanhf(gg);
            float hn = sigf(go)*tanhf(c1s);
            u16 hh_ = f2bf(hn);
            u16 hl_ = f2bf(hn - bf2f(hh_));
            (hb + 262144 + wro)[poff] = hh_;
            (hb + 393216 + wro)[poff] = hl_;
        }
        // ---- prefetch-stage x(k+1) into parity (k+1)&1 (fragment order) ----
        if (k + 1 < TT) {
            int r = tid & 31, c8 = tid >> 5;
            const float* xp = x + (size_t)(rbase + r)*(TT*DIN) + (size_t)(k+1)*DIN + c8*8;
            bf16x8 xh, xl;
            split8(*(const float4*)xp, *(const float4*)(xp+4), xh, xl);
            int pb = ((k+1)&1)*4096;
            int fo = ((c8>>2)*2 + (r>>4))*512 + ((c8&3)*16 + (r&15))*8;
            *(bf16x8*)(sh + OFF_XS + pb + fo)        = xh;
            *(bf16x8*)(sh + OFF_XS + pb + 2048 + fo) = xl;
        }
        group_barrier(flg, ug, (unsigned)(k+2));
    }

    // ---- dense head: out = h1(T-1) @ Wd^T + bd ; h1(T-1) in parity-0 planes ----
    if (ug == 0 && tid < 64) {
        int r = tid >> 1, j = tid & 1;
        const u16* hhp = hb + 262144 + (size_t)(rbase + r)*HH;
        const u16* hlp = hb + 393216 + (size_t)(rbase + r)*HH;
        const float* wdp = Wd + j*HH;
        float a = bd[j];
        #pragma unroll 4
        for (int q = 0; q < HH; ++q)
            a += (bf2f(hhp[q]) + bf2f(hlp[q])) * wdp[q];
        out[(rbase + r)*2 + j] = a;
    }
}

extern "C" void kernel_launch(void* const* d_in, const int* in_sizes, int n_in,
                              void* d_out, int out_size, void* d_ws, size_t ws_size,
                              hipStream_t stream) {
    const float* x    = (const float*)d_in[0];
    const float* Wih0 = (const float*)d_in[1];
    const float* Whh0 = (const float*)d_in[2];
    const float* bih0 = (const float*)d_in[3];
    const float* bhh0 = (const float*)d_in[4];
    const float* Wih1 = (const float*)d_in[5];
    const float* Whh1 = (const float*)d_in[6];
    const float* bih1 = (const float*)d_in[7];
    const float* bhh1 = (const float*)d_in[8];
    const float* Wd   = (const float*)d_in[9];
    const float* bd   = (const float*)d_in[10];
    float* out = (float*)d_out;

    u32t* flags = (u32t*)d_ws;                     // 16 KB: 8 groups x 32 WGs x 64B
    u16* hb = (u16*)((char*)d_ws + 32768);         // 1 MB h hi/lo planes

    hipMemsetAsync(d_ws, 0, 32768, stream);

    hipFuncSetAttribute((const void*)lstm_v7,
                        hipFuncAttributeMaxDynamicSharedMemorySize, LDS_BYTES);

    lstm_v7<<<dim3(256), dim3(256), LDS_BYTES, stream>>>(
        x, Wih0, Whh0, bih0, bhh0, Wih1, Whh1, bih1, bhh1,
        Wd, bd, out, hb, flags);
}

// Round 8
// 17004.735 us; speedup vs baseline: 3.2922x; 1.3567x over previous
//
#include <hip/hip_runtime.h>
#include <math.h>

#define TT 2048
#define DIN 64
#define HH 256

typedef __attribute__((ext_vector_type(8))) short bf16x8;
typedef __attribute__((ext_vector_type(4))) float f32x4;
typedef __attribute__((ext_vector_type(4))) unsigned u32x4;
typedef unsigned short u16;
typedef unsigned u32t;

// ---- LDS layout (identical to round-4 verified kernel) ----
#define XS_STR 72    // x stage row stride (64 + 8 pad)
#define HS_STR 264   // h stage row stride (256 + 8 pad)
#define GB_STR 36    // gate buffer row stride (32 + 4 pad)

#define OFF_XS_HI  0
#define OFF_XS_LO  (OFF_XS_HI + 32*XS_STR)     // 2304
#define OFF_HS0_HI (OFF_XS_LO + 32*XS_STR)     // 4608
#define OFF_HS0_LO (OFF_HS0_HI + 32*HS_STR)    // 13056
#define OFF_HS1_HI (OFF_HS0_LO + 32*HS_STR)    // 21504
#define OFF_HS1_LO (OFF_HS1_HI + 32*HS_STR)    // 29952
#define OFF_W0LO   (OFF_HS1_LO + 32*HS_STR)    // 38400
#define OFF_W1LO   (OFF_W0LO + 1280*8)         // 48640
#define SH_SHORTS  (OFF_W1LO + 2048*8)         // 65024 shorts
#define SH_BYTES   (SH_SHORTS*2)               // 130048 B
#define LDS_BYTES  (SH_BYTES + 2368*4)         // 139520 B

__device__ __forceinline__ u16 f2bf(float f){
    u32t u = __builtin_bit_cast(u32t, f);
    u += 0x7fffu + ((u >> 16) & 1u);   // RNE
    return (u16)(u >> 16);
}
__device__ __forceinline__ float bf2f(u16 h){
    u32t u = ((u32t)h) << 16;
    return __builtin_bit_cast(float, u);
}
__device__ __forceinline__ float sigf(float v){ return 1.0f/(1.0f+__expf(-v)); }
__device__ __forceinline__ float tanh_fast(float v){
    float x = fminf(fmaxf(v, -20.f), 20.f);
    float t = __expf(2.f*x);
    return (t - 1.f) / (t + 1.f);
}

__device__ __forceinline__ void split8(float4 a, float4 b, bf16x8& hi, bf16x8& lo){
    float v[8] = {a.x,a.y,a.z,a.w,b.x,b.y,b.z,b.w};
    #pragma unroll
    for (int j=0;j<8;++j){
        u16 h = f2bf(v[j]);
        hi[j] = (short)h;
        lo[j] = (short)f2bf(v[j] - bf2f(h));
    }
}

// Parallel flag barrier, volatile protocol (no atomics, no cache-maint ops):
// __syncthreads() emits s_waitcnt vmcnt(0) for every wave -> all volatile h
// stores are acked at the coherence point before thread 0 stores the flag.
// Volatile accesses bypass L1/L2 -> always coherent, any XCD mapping.
__device__ __forceinline__ void group_barrier(u32t* flg, int ug, unsigned epoch){
    __syncthreads();
    if (threadIdx.x == 0){
        asm volatile("s_waitcnt vmcnt(0)" ::: "memory");
        *(volatile u32t*)(flg + ug*16) = epoch;
    }
    if (threadIdx.x < 32){
        while (*(volatile u32t*)(flg + threadIdx.x*16) < epoch)
            __builtin_amdgcn_s_sleep(1);
    }
    __syncthreads();
}

#define MFMA16(a,b,c_) __builtin_amdgcn_mfma_f32_16x16x32_bf16(a,b,c_,0,0,0)

__global__ __launch_bounds__(256, 1)
void lstm_v8(const float* __restrict__ x,
             const float* __restrict__ Wih0, const float* __restrict__ Whh0,
             const float* __restrict__ bih0, const float* __restrict__ bhh0,
             const float* __restrict__ Wih1, const float* __restrict__ Whh1,
             const float* __restrict__ bih1, const float* __restrict__ bhh1,
             const float* __restrict__ Wd,   const float* __restrict__ bd,
             float* __restrict__ out, u16* __restrict__ hb,
             u32t* __restrict__ flags)
{
    extern __shared__ char smem[];
    short* sh  = (short*)smem;
    float* sf  = (float*)(smem + SH_BYTES);
    float* gb0 = sf;             // [32][36]
    float* gb1 = sf + 1152;      // [32][36]
    float* b0s = sf + 2304;      // [32]
    float* b1s = sf + 2336;      // [32]

    const int tid = threadIdx.x;
    const int w   = blockIdx.x;
    const int rb  = w & 7;      // row-group
    const int ug  = w >> 3;     // unit-group 0..31
    const int rbase = rb * 32;
    const int u0  = ug * 8;

    u32t* flg = flags + rb * 512;

    // h planes (u16): h0hi,h0lo,h1hi,h1lo at p*131072, + parity*65536

    const int l  = tid & 63;
    const int wv = tid >> 6;
    const int mt = wv >> 1, nt = wv & 1;
    const int c  = l & 15, ks = l >> 4;
    const int gbx = nt*2 + (c >> 3);
    const int g   = gbx*HH + u0 + (c & 7);

    // ---- stationary HI weight fragments in registers ----
    bf16x8 w0h[10];
    #pragma unroll
    for (int kt = 0; kt < 10; ++kt) {
        int k = kt*32 + ks*8;
        const float* p = (k < 64) ? (Wih0 + (size_t)g*64 + k)
                                  : (Whh0 + (size_t)g*HH + (k - 64));
        bf16x8 hi_, lo_;
        split8(*(const float4*)p, *(const float4*)(p+4), hi_, lo_);
        w0h[kt] = hi_;
    }
    bf16x8 w1h[16];
    #pragma unroll
    for (int kt = 0; kt < 16; ++kt) {
        int k = kt*32 + ks*8;
        const float* p = (k < 256) ? (Wih1 + (size_t)g*HH + k)
                                   : (Whh1 + (size_t)g*HH + (k - 256));
        bf16x8 hi_, lo_;
        split8(*(const float4*)p, *(const float4*)(p+4), hi_, lo_);
        w1h[kt] = hi_;
    }
    // ---- LO weight fragments into LDS, slot = kt*128 + nt*64 + ks*16 + c ----
    for (int f = tid; f < 1280; f += 256) {
        int c_ = f & 15, ks_ = (f>>4)&3, nt_ = (f>>6)&1, kt_ = f>>7;
        int g_ = (nt_*2 + (c_>>3))*HH + u0 + (c_&7);
        int k_ = kt_*32 + ks_*8;
        const float* p = (k_ < 64) ? (Wih0 + (size_t)g_*64 + k_)
                                   : (Whh0 + (size_t)g_*HH + (k_ - 64));
        bf16x8 hi_, lo_;
        split8(*(const float4*)p, *(const float4*)(p+4), hi_, lo_);
        *(bf16x8*)(sh + OFF_W0LO + f*8) = lo_;
    }
    for (int f = tid; f < 2048; f += 256) {
        int c_ = f & 15, ks_ = (f>>4)&3, nt_ = (f>>6)&1, kt_ = f>>7;
        int g_ = (nt_*2 + (c_>>3))*HH + u0 + (c_&7);
        int k_ = kt_*32 + ks_*8;
        const float* p = (k_ < 256) ? (Wih1 + (size_t)g_*HH + k_)
                                    : (Whh1 + (size_t)g_*HH + (k_ - 256));
        bf16x8 hi_, lo_;
        split8(*(const float4*)p, *(const float4*)(p+4), hi_, lo_);
        *(bf16x8*)(sh + OFF_W1LO + f*8) = lo_;
    }

    if (tid < 32) {
        int gg_ = (tid >> 3)*HH + u0 + (tid & 7);
        b0s[tid] = bih0[gg_] + bhh0[gg_];
        b1s[tid] = bih1[gg_] + bhh1[gg_];
    }
    // ---- zero my h slots, all planes/parities (ws poisoned) ----
    {
        int zr = tid >> 3, zu = tid & 7;
        size_t off = (size_t)(rbase + zr)*HH + u0 + zu;
        *(volatile u16*)(hb + off) = 0;          *(volatile u16*)(hb + 65536 + off) = 0;
        *(volatile u16*)(hb + 131072 + off) = 0; *(volatile u16*)(hb + 196608 + off) = 0;
        *(volatile u16*)(hb + 262144 + off) = 0; *(volatile u16*)(hb + 327680 + off) = 0;
        *(volatile u16*)(hb + 393216 + off) = 0; *(volatile u16*)(hb + 458752 + off) = 0;
    }
    // ---- stage x(0) ----
    {
        int xr = tid >> 3, xk = (tid & 7)*8;
        const float* xp = x + (size_t)(rbase + xr)*(TT*DIN) + xk;
        bf16x8 xh, xl;
        split8(*(const float4*)xp, *(const float4*)(xp+4), xh, xl);
        *(bf16x8*)(sh + OFF_XS_HI + xr*XS_STR + xk) = xh;
        *(bf16x8*)(sh + OFF_XS_LO + xr*XS_STR + xk) = xl;
    }
    group_barrier(flg, ug, 1u);

    // A-frag LDS base pointers
    const short* axh = sh + OFF_XS_HI  + (mt*16 + c)*XS_STR + ks*8;
    const short* axl = sh + OFF_XS_LO  + (mt*16 + c)*XS_STR + ks*8;
    const short* a0h = sh + OFF_HS0_HI + (mt*16 + c)*HS_STR + ks*8;
    const short* a0l = sh + OFF_HS0_LO + (mt*16 + c)*HS_STR + ks*8;
    const short* a1h = sh + OFF_HS1_HI + (mt*16 + c)*HS_STR + ks*8;
    const short* a1l = sh + OFF_HS1_LO + (mt*16 + c)*HS_STR + ks*8;
    const short* b0lo = sh + OFF_W0LO + (nt*64 + ks*16 + c)*8;
    const short* b1lo = sh + OFF_W1LO + (nt*64 + ks*16 + c)*8;
    float* gw0 = gb0 + (mt*16 + ks*4)*GB_STR + nt*16 + c;
    float* gw1 = gb1 + (mt*16 + ks*4)*GB_STR + nt*16 + c;
    const int ur = tid >> 3, uu = tid & 7;
    const size_t poff = (size_t)(rbase + ur)*HH + u0 + uu;

    float c0s = 0.f, c1s = 0.f;

    for (int k = 0; k <= TT; ++k) {
        // ---- stage h0(k-1), h1(k-2) from planes (volatile: coherent reads) ----
        {
            const unsigned rdo = ((k + 1) & 1) * 65536u;
            const u16* s0h = hb + rdo;
            const u16* s0l = hb + 131072 + rdo;
            const u16* s1h = hb + 262144 + rdo;
            const u16* s1l = hb + 393216 + rdo;
            #pragma unroll
            for (int j = 0; j < 4; ++j) {
                int cid = tid + j*256;
                int hr = cid >> 5, hk = (cid & 31)*8;
                size_t goff = (size_t)(rbase + hr)*HH + hk;
                int loff = hr*HS_STR + hk;
                *(u32x4*)(sh + OFF_HS0_HI + loff) = *(const volatile u32x4*)(s0h + goff);
                *(u32x4*)(sh + OFF_HS0_LO + loff) = *(const volatile u32x4*)(s0l + goff);
                *(u32x4*)(sh + OFF_HS1_HI + loff) = *(const volatile u32x4*)(s1h + goff);
                *(u32x4*)(sh + OFF_HS1_LO + loff) = *(const volatile u32x4*)(s1l + goff);
            }
        }
        __syncthreads();

        // ---- phase A: layer0 step t=k ----
        if (k < TT) {
            f32x4 ac[4] = {};
            #pragma unroll
            for (int kt = 0; kt < 10; ++kt) {
                const short* ph = (kt < 2) ? (axh + kt*32) : (a0h + (kt-2)*32);
                const short* pl = (kt < 2) ? (axl + kt*32) : (a0l + (kt-2)*32);
                bf16x8 ah = *(const bf16x8*)ph;
                bf16x8 al = *(const bf16x8*)pl;
                bf16x8 wl = *(const bf16x8*)(b0lo + kt*1024);
                const int q = kt & 3;
                ac[q] = MFMA16(ah, w0h[kt], ac[q]);
                ac[q] = MFMA16(al, w0h[kt], ac[q]);
                ac[q] = MFMA16(ah, wl,      ac[q]);
            }
            f32x4 aa = (ac[0] + ac[1]) + (ac[2] + ac[3]);
            gw0[0]        = aa[0];
            gw0[GB_STR]   = aa[1];
            gw0[2*GB_STR] = aa[2];
            gw0[3*GB_STR] = aa[3];
        }
        // ---- phase B: layer1 step t=k-1 ----
        if (k >= 1) {
            f32x4 ac[4] = {};
            #pragma unroll
            for (int kt = 0; kt < 16; ++kt) {
                const short* ph = (kt < 8) ? (a0h + kt*32) : (a1h + (kt-8)*32);
                const short* pl = (kt < 8) ? (a0l + kt*32) : (a1l + (kt-8)*32);
                bf16x8 ah = *(const bf16x8*)ph;
                bf16x8 al = *(const bf16x8*)pl;
                bf16x8 wl = *(const bf16x8*)(b1lo + kt*1024);
                const int q = kt & 3;
                ac[q] = MFMA16(ah, w1h[kt], ac[q]);
                ac[q] = MFMA16(al, w1h[kt], ac[q]);
                ac[q] = MFMA16(ah, wl,      ac[q]);
            }
            f32x4 aa = (ac[0] + ac[1]) + (ac[2] + ac[3]);
            gw1[0]        = aa[0];
            gw1[GB_STR]   = aa[1];
            gw1[2*GB_STR] = aa[2];
            gw1[3*GB_STR] = aa[3];
        }
        __syncthreads();

        // ---- cell updates + publish (volatile stores -> coherence point) ----
        const unsigned wro = (k & 1) * 65536u;
        if (k < TT) {
            float gi = gb0[ur*GB_STR + uu]      + b0s[uu];
            float gf = gb0[ur*GB_STR + 8 + uu]  + b0s[8+uu];
            float gg = gb0[ur*GB_STR + 16 + uu] + b0s[16+uu];
            float go = gb0[ur*GB_STR + 24 + uu] + b0s[24+uu];
            c0s = sigf(gf)*c0s + sigf(gi)*tanh_fast(gg);
            float hn = sigf(go)*tanh_fast(c0s);
            u16 hh_ = f2bf(hn);
            u16 hl_ = f2bf(hn - bf2f(hh_));
            *(volatile u16*)(hb + wro + poff)          = hh_;
            *(volatile u16*)(hb + 131072 + wro + poff) = hl_;
        }
        if (k >= 1) {
            float gi = gb1[ur*GB_STR + uu]      + b1s[uu];
            float gf = gb1[ur*GB_STR + 8 + uu]  + b1s[8+uu];
            float gg = gb1[ur*GB_STR + 16 + uu] + b1s[16+uu];
            float go = gb1[ur*GB_STR + 24 + uu] + b1s[24+uu];
            c1s = sigf(gf)*c1s + sigf(gi)*tanh_fast(gg);
            float hn = sigf(go)*tanh_fast(c1s);
            u16 hh_ = f2bf(hn);
            u16 hl_ = f2bf(hn - bf2f(hh_));
            *(volatile u16*)(hb + 262144 + wro + poff) = hh_;
            *(volatile u16*)(hb + 393216 + wro + poff) = hl_;
        }
        // ---- prefetch-stage x(k+1) ----
        if (k + 1 < TT) {
            int xr = tid >> 3, xk = (tid & 7)*8;
            const float* xp = x + (size_t)(rbase + xr)*(TT*DIN) + (size_t)(k+1)*DIN + xk;
            bf16x8 xh, xl;
            split8(*(const float4*)xp, *(const float4*)(xp+4), xh, xl);
            *(bf16x8*)(sh + OFF_XS_HI + xr*XS_STR + xk) = xh;
            *(bf16x8*)(sh + OFF_XS_LO + xr*XS_STR + xk) = xl;
        }
        group_barrier(flg, ug, (unsigned)(k+2));
    }

    // ---- dense head: out = h1(T-1) @ Wd^T + bd ; h1(T-1) in parity-0 planes ----
    if (ug == 0 && tid < 64) {
        int r = tid >> 1, j = tid & 1;
        const u16* hhp = hb + 262144 + (size_t)(rbase + r)*HH;
        const u16* hlp = hb + 393216 + (size_t)(rbase + r)*HH;
        const float* wdp = Wd + j*HH;
        float a = bd[j];
        #pragma unroll 4
        for (int q = 0; q < HH; ++q)
            a += (bf2f(*(const volatile u16*)(hhp + q)) +
                  bf2f(*(const volatile u16*)(hlp + q))) * wdp[q];
        out[(rbase + r)*2 + j] = a;
    }
}

extern "C" void kernel_launch(void* const* d_in, const int* in_sizes, int n_in,
                              void* d_out, int out_size, void* d_ws, size_t ws_size,
                              hipStream_t stream) {
    const float* x    = (const float*)d_in[0];
    const float* Wih0 = (const float*)d_in[1];
    const float* Whh0 = (const float*)d_in[2];
    const float* bih0 = (const float*)d_in[3];
    const float* bhh0 = (const float*)d_in[4];
    const float* Wih1 = (const float*)d_in[5];
    const float* Whh1 = (const float*)d_in[6];
    const float* bih1 = (const float*)d_in[7];
    const float* bhh1 = (const float*)d_in[8];
    const float* Wd   = (const float*)d_in[9];
    const float* bd   = (const float*)d_in[10];
    float* out = (float*)d_out;

    u32t* flags = (u32t*)d_ws;                     // 16 KB: 8 groups x 32 WGs x 64B
    u16* hb = (u16*)((char*)d_ws + 32768);         // 1 MB h hi/lo planes

    hipMemsetAsync(d_ws, 0, 32768, stream);

    hipFuncSetAttribute((const void*)lstm_v8,
                        hipFuncAttributeMaxDynamicSharedMemorySize, LDS_BYTES);

    lstm_v8<<<dim3(256), dim3(256), LDS_BYTES, stream>>>(
        x, Wih0, Whh0, bih0, bhh0, Wih1, Whh1, bih1, bhh1,
        Wd, bd, out, hb, flags);
}